// Round 6
// baseline (186.294 us; speedup 1.0000x reference)
//
#include <hip/hip_runtime.h>
#include <hip/hip_bf16.h>
#include <stdint.h>

// Problem constants
#define BB  2
#define LL  1024
#define DMM 768
#define DII 1536
#define NSS 16
#define DTRR 48
#define XZN (2*DII)        // 3072
#define NROWS (BB*LL)      // 2048
#define N2 1664            // padded N for combined GEMM2 (1536 dmod + 32 B/C + 96 pad)

// chunked scan: one thread per (b, d, chunk), 16 n-states in registers
#define CHUNKS 32
#define CHLEN  (LL/CHUNKS)          // 32
#define NCH    (BB*DII*NSS)         // 49152 channels for p2

typedef _Float16 h16;
typedef __attribute__((ext_vector_type(8))) _Float16 h16x8;
typedef __attribute__((ext_vector_type(4))) float f32x4;

typedef const __attribute__((address_space(1))) uint32_t gau32;
typedef __attribute__((address_space(3))) uint32_t lau32;
#define GLL16(gp, lp) __builtin_amdgcn_global_load_lds((gau32*)(gp), (lau32*)(lp), 16, 0, 0)

__device__ __forceinline__ float dspf(float x) {
    return 0.25f * (x + sqrtf(x*x + 4.0f));
}
__device__ __forceinline__ float clampf(float x, float lo, float hi) {
    return fminf(fmaxf(x, lo), hi);
}

// ---------------------------------------------------------------------------
// f32 -> f16 convert
// ---------------------------------------------------------------------------
__global__ __launch_bounds__(256) void k_cvt(const float* __restrict__ in,
                                             h16* __restrict__ out, int n) {
    int i = blockIdx.x * 256 + threadIdx.x;
    if (i < n) out[i] = (h16)in[i];
}

// ---------------------------------------------------------------------------
// Build combined W2 [N2 x DII] (f16) + bias2 [N2] (f32)
// ---------------------------------------------------------------------------
__global__ __launch_bounds__(256) void k_w2(const float* __restrict__ W_x,
                                            const float* __restrict__ b_x,
                                            const float* __restrict__ W_dt,
                                            const float* __restrict__ b_dt,
                                            h16* __restrict__ W2,
                                            float* __restrict__ bias2) {
    int i = blockIdx.x;
    int tid = threadIdx.x;
    if (i < DII) {
        __shared__ float wd[DTRR];
        if (tid < DTRR) wd[tid] = W_dt[i * DTRR + tid];
        __syncthreads();
        for (int j = tid; j < DII; j += 256) {
            float s = 0.f;
            #pragma unroll
            for (int k = 0; k < DTRR; ++k) s = fmaf(wd[k], W_x[(size_t)k * DII + j], s);
            W2[(size_t)i * DII + j] = (h16)s;
        }
        if (tid == 0) {
            float s = b_dt[i];
            for (int k = 0; k < DTRR; ++k) s = fmaf(wd[k], b_x[k], s);
            bias2[i] = s;
        }
    } else if (i < DII + 2 * NSS) {
        int r = i - DII;
        for (int j = tid; j < DII; j += 256)
            W2[(size_t)i * DII + j] = (h16)W_x[(size_t)(DTRR + r) * DII + j];
        if (tid == 0) bias2[i] = b_x[DTRR + r];
    } else {
        for (int j = tid; j < DII; j += 256) W2[(size_t)i * DII + j] = (h16)0.f;
        if (tid == 0) bias2[i] = 0.f;
    }
}

// ---------------------------------------------------------------------------
// K1: norm -> f16 output
// ---------------------------------------------------------------------------
__global__ __launch_bounds__(256) void k_norm(const float* __restrict__ hs,
                                              const float* __restrict__ gamma,
                                              h16* __restrict__ out) {
    int row = blockIdx.x;
    const float* p = hs + (size_t)row * DMM;
    __shared__ float red[256];
    int tid = threadIdx.x;

    float s = 0.f;
    for (int i = tid; i < DMM; i += 256) s += p[i];
    red[tid] = s; __syncthreads();
    for (int off = 128; off > 0; off >>= 1) {
        if (tid < off) red[tid] += red[tid + off];
        __syncthreads();
    }
    float mean = red[0] / (float)DMM;
    __syncthreads();

    float v = 0.f;
    for (int i = tid; i < DMM; i += 256) { float d = p[i] - mean; v += d*d; }
    red[tid] = v; __syncthreads();
    for (int off = 128; off > 0; off >>= 1) {
        if (tid < off) red[tid] += red[tid + off];
        __syncthreads();
    }
    float var = red[0] / (float)DMM;
    float k = rintf(log2f(sqrtf(var + 1e-9f)));
    k = fmaxf(k, 0.f);
    float scale = exp2f(-k);
    for (int i = tid; i < DMM; i += 256)
        out[(size_t)row * DMM + i] = (h16)((p[i] - mean) * scale * gamma[i]);
}

// ---------------------------------------------------------------------------
// MFMA f16 GEMM, 64x64 tile, BK=64, 4 waves (each 32x32), double-buffered
// LDS with counted vmcnt(4). Templated output type. XCD-bijective block
// swizzle (grid must be a multiple of 8 blocks, all our launches are).
// EPI==1: out = resid + clip(acc+bias,±32000)*rg
// ---------------------------------------------------------------------------
template<int EPI, typename OutT>
__global__ __launch_bounds__(256) void k_gemm64(
    const h16* __restrict__ A, int lda,
    const h16* __restrict__ Bw, int ldb,
    const float* __restrict__ bias,
    OutT* __restrict__ C, int ldc, int K,
    const float* __restrict__ resid, const float* __restrict__ rgate)
{
    __shared__ __align__(16) h16 As[2][64 * 64];
    __shared__ __align__(16) h16 Bs[2][64 * 64];
    const int tid  = threadIdx.x;
    const int lane = tid & 63;
    const int wv   = tid >> 6;

    // XCD-aware bijective swizzle of the flat block id
    const int nwg = gridDim.x * gridDim.y;
    const int bid = blockIdx.y * gridDim.x + blockIdx.x;
    const int cpx = nwg >> 3;
    const int swz = (bid & 7) * cpx + (bid >> 3);
    const int bxi = swz % gridDim.x, byi = swz / gridDim.x;

    const int bm = byi * 64, bn = bxi * 64;
    const int wr = wv >> 1, wc = wv & 1;

    f32x4 acc[2][2] = {};

    const int srow = lane >> 3;                    // row within 8-row issue
    const int kbl  = ((lane & 7) ^ srow) * 8;      // pre-swizzled logical k-block
    const int KT = K / 64;

    #pragma unroll
    for (int q = 0; q < 2; ++q) {
        int row = (wv * 2 + q) * 8 + srow;
        GLL16(A  + (size_t)(bm + row) * lda + kbl, &As[0][(wv*2+q)*8*64]);
        GLL16(Bw + (size_t)(bn + row) * ldb + kbl, &Bs[0][(wv*2+q)*8*64]);
    }

    int buf = 0;
    for (int kt = 0; kt < KT; ++kt) {
        if (kt + 1 < KT) {
            int k0 = (kt + 1) * 64;
            #pragma unroll
            for (int q = 0; q < 2; ++q) {
                int row = (wv * 2 + q) * 8 + srow;
                GLL16(A  + (size_t)(bm + row) * lda + k0 + kbl, &As[buf^1][(wv*2+q)*8*64]);
                GLL16(Bw + (size_t)(bn + row) * ldb + k0 + kbl, &Bs[buf^1][(wv*2+q)*8*64]);
            }
            asm volatile("s_waitcnt vmcnt(4)" ::: "memory");
        } else {
            asm volatile("s_waitcnt vmcnt(0)" ::: "memory");
        }
        __syncthreads();

        const int r16 = lane & 15, kq = lane >> 4;
        #pragma unroll
        for (int kk = 0; kk < 2; ++kk) {
            h16x8 af[2], bf[2];
            #pragma unroll
            for (int i = 0; i < 2; ++i) {
                int rowA = wr * 32 + i * 16 + r16;
                af[i] = *(const h16x8*)&As[buf][rowA * 64 + (((kk*4 + kq) ^ (rowA & 7)) << 3)];
            }
            #pragma unroll
            for (int j = 0; j < 2; ++j) {
                int rowB = wc * 32 + j * 16 + r16;
                bf[j] = *(const h16x8*)&Bs[buf][rowB * 64 + (((kk*4 + kq) ^ (rowB & 7)) << 3)];
            }
            #pragma unroll
            for (int i = 0; i < 2; ++i)
                #pragma unroll
                for (int j = 0; j < 2; ++j)
                    acc[i][j] = __builtin_amdgcn_mfma_f32_16x16x32_f16(af[i], bf[j], acc[i][j], 0, 0, 0);
        }
        __syncthreads();
        buf ^= 1;
    }

    const int r4 = (lane >> 4) * 4;
    const int cn = lane & 15;
    float rg = 0.f;
    if (EPI) rg = rgate[0];
    #pragma unroll
    for (int i = 0; i < 2; ++i) {
        #pragma unroll
        for (int j = 0; j < 2; ++j) {
            int col = bn + wc * 32 + j * 16 + cn;
            float bv = bias[col];
            #pragma unroll
            for (int r = 0; r < 4; ++r) {
                int row = bm + wr * 32 + i * 16 + r4 + r;
                float v = acc[i][j][r] + bv;
                if (EPI) {
                    v = clampf(v, -32000.f, 32000.f);
                    v = resid[(size_t)row * ldc + col] + v * rg;
                }
                C[(size_t)row * ldc + col] = (OutT)v;
            }
        }
    }
}

// ---------------------------------------------------------------------------
// K3: depthwise causal conv (f16 in) + dsp -> f16 xact
// ---------------------------------------------------------------------------
__global__ __launch_bounds__(256) void k_conv(const h16* __restrict__ xz,
                                              const float* __restrict__ cw,
                                              const float* __restrict__ cb,
                                              h16* __restrict__ xacth)
{
    int idx = blockIdx.x * 256 + threadIdx.x;       // over B*L*DI
    if (idx >= NROWS * DII) return;
    int c = idx % DII;
    int bl = idx / DII;
    int l = bl % LL;
    int b = bl / LL;
    float acc = cb[c];
    #pragma unroll
    for (int j = 0; j < 4; ++j) {
        int ls = l - 3 + j;
        if (ls >= 0)
            acc = fmaf((float)xz[(size_t)(b * LL + ls) * XZN + c], cw[c * 4 + j], acc);
    }
    xacth[idx] = (h16)dspf(acc);
}

// ---------------------------------------------------------------------------
// Chunked scan. Thread = (b, chunk, d); 16 n-states in registers.
// stA/stH split arrays, index ((b*CHUNKS+chunk)*DII + d)*16 + n.
// p1 writes (A-product, h-end); p2 rewrites stA to the incoming prefix;
// p3 reads only stA.
// ---------------------------------------------------------------------------
__global__ __launch_bounds__(256) void k_scan_p1(
    const h16* __restrict__ dmbc,      // (B*L, N2) f16: [dmod 1536 | B 16 | C 16 | pad]
    const h16* __restrict__ xacth,     // (B*L, DI)
    const float* __restrict__ basenum, // (DI, NS)
    const int*   __restrict__ shifts,  // (DI, NS)
    float* __restrict__ stA, float* __restrict__ stH)
{
    int bc   = blockIdx.x / 6;              // b*CHUNKS + chunk  (uniform)
    int dblk = blockIdx.x % 6;
    int d    = dblk * 256 + threadIdx.x;
    int b    = bc / CHUNKS;
    int chunk= bc % CHUNKS;

    float base[16], p2c[16], h[16], A[16];
    #pragma unroll
    for (int n = 0; n < 16; ++n) {
        base[n] = basenum[d * NSS + n];
        p2c[n]  = exp2f(-(float)shifts[d * NSS + n]);
        h[n] = 0.f; A[n] = 1.f;
    }
    int row0 = b * LL + chunk * CHLEN;
    #pragma unroll 2
    for (int l = 0; l < CHLEN; ++l) {
        int row = row0 + l;
        float dm = (float)dmbc[(size_t)row * N2 + d];
        float xv = (float)xacth[(size_t)row * DII + d];
        float common = xv * (dspf(dm) * 0.1f);
        const h16x8* Bp = (const h16x8*)(dmbc + (size_t)row * N2 + DII);
        h16x8 b0 = Bp[0], b1 = Bp[1];
        float Bv[16];
        #pragma unroll
        for (int n = 0; n < 8; ++n) { Bv[n] = (float)b0[n]; Bv[8+n] = (float)b1[n]; }
        #pragma unroll
        for (int n = 0; n < 16; ++n) {
            float a = clampf(base[n] + dm, 0.f, 32767.f) * p2c[n];
            h[n] = fmaf(a, h[n], common * Bv[n]);
            A[n] *= a;
        }
    }
    size_t sb = ((size_t)bc * DII + d) * 16;
    #pragma unroll
    for (int n = 0; n < 16; ++n) { stA[sb + n] = A[n]; stH[sb + n] = h[n]; }
}

__global__ __launch_bounds__(256) void k_scan_p2(float* __restrict__ stA,
                                                 const float* __restrict__ stH)
{
    int ch = blockIdx.x * 256 + threadIdx.x;   // b*(DII*NSS) + d*16 + n
    int b  = ch / (DII * NSS);
    int rem = ch - b * (DII * NSS);
    float hin = 0.f;
    #pragma unroll 4
    for (int c = 0; c < CHUNKS; ++c) {
        size_t idx = ((size_t)(b * CHUNKS + c) * (DII * NSS)) + rem;
        float a = stA[idx], hh = stH[idx];
        stA[idx] = hin;
        hin = fmaf(a, hin, hh);
    }
}

__global__ __launch_bounds__(256) void k_scan_p3(
    const h16* __restrict__ dmbc,
    const h16* __restrict__ xacth,
    const h16* __restrict__ xz,        // for z -> gate
    const float* __restrict__ basenum,
    const int*   __restrict__ shifts,
    const float* __restrict__ stA,
    h16* __restrict__ ygh)             // (B*L, DI) = y * gate(z), f16
{
    int bc   = blockIdx.x / 6;
    int dblk = blockIdx.x % 6;
    int d    = dblk * 256 + threadIdx.x;
    int b    = bc / CHUNKS;
    int chunk= bc % CHUNKS;

    float base[16], p2c[16], h[16];
    size_t sb = ((size_t)bc * DII + d) * 16;
    #pragma unroll
    for (int n = 0; n < 16; ++n) {
        base[n] = basenum[d * NSS + n];
        p2c[n]  = exp2f(-(float)shifts[d * NSS + n]);
        h[n] = stA[sb + n];            // incoming prefix
    }
    int row0 = b * LL + chunk * CHLEN;
    #pragma unroll 2
    for (int l = 0; l < CHLEN; ++l) {
        int row = row0 + l;
        float dm = (float)dmbc[(size_t)row * N2 + d];
        float xv = (float)xacth[(size_t)row * DII + d];
        float common = xv * (dspf(dm) * 0.1f);
        const h16x8* Bp = (const h16x8*)(dmbc + (size_t)row * N2 + DII);
        h16x8 b0 = Bp[0], b1 = Bp[1], c0 = Bp[2], c1 = Bp[3];
        float Bv[16], Cv[16];
        #pragma unroll
        for (int n = 0; n < 8; ++n) {
            Bv[n] = (float)b0[n]; Bv[8+n] = (float)b1[n];
            Cv[n] = (float)c0[n]; Cv[8+n] = (float)c1[n];
        }
        float y = 0.f;
        #pragma unroll
        for (int n = 0; n < 16; ++n) {
            float a = clampf(base[n] + dm, 0.f, 32767.f) * p2c[n];
            h[n] = fmaf(a, h[n], common * Bv[n]);
            float hc = clampf(h[n], -32000.f, 32000.f);
            y = fmaf(hc, Cv[n], y);
        }
        float z = (float)xz[(size_t)row * XZN + DII + d];
        float gate = 0.5f * (1.0f + z * rsqrtf(z * z + 1.0f));
        ygh[(size_t)row * DII + d] = (h16)(y * gate);
    }
}

// ---------------------------------------------------------------------------
extern "C" void kernel_launch(void* const* d_in, const int* in_sizes, int n_in,
                              void* d_out, int out_size, void* d_ws, size_t ws_size,
                              hipStream_t stream) {
    const float* hs        = (const float*)d_in[0];
    const float* gamma     = (const float*)d_in[1];
    const float* W_in      = (const float*)d_in[2];
    const float* b_in      = (const float*)d_in[3];
    const float* conv_w    = (const float*)d_in[4];
    const float* conv_b    = (const float*)d_in[5];
    const float* W_x       = (const float*)d_in[6];
    const float* b_x       = (const float*)d_in[7];
    const float* W_dt      = (const float*)d_in[8];
    const float* b_dt      = (const float*)d_in[9];
    const float* W_out     = (const float*)d_in[10];
    const float* b_out     = (const float*)d_in[11];
    const float* base_dec  = (const float*)d_in[12];
    const float* res_gate  = (const float*)d_in[13];
    const int*   dec_shift = (const int*)d_in[14];

    // workspace layout (bytes), no overlays
    char* w = (char*)d_ws;
    h16*   XZH   = (h16*)w;    w += (size_t)NROWS * XZN * 2;   // 12.6 MB
    h16*   XACTH = (h16*)w;    w += (size_t)NROWS * DII * 2;   //  6.3 MB
    h16*   DMBCH = (h16*)w;    w += (size_t)NROWS * N2  * 2;   //  6.8 MB
    h16*   W2H   = (h16*)w;    w += (size_t)N2 * DII * 2;      //  5.1 MB
    h16*   WOH   = (h16*)w;    w += (size_t)DMM * DII * 2;     //  2.4 MB
    float* BIAS2 = (float*)w;  w += 8192;
    h16*   YGH   = (h16*)w;    w += (size_t)NROWS * DII * 2;   //  6.3 MB
    h16*   HSNH  = (h16*)w;    w += (size_t)NROWS * DMM * 2;   //  3.1 MB
    h16*   WINH  = (h16*)w;    w += (size_t)XZN * DMM * 2;     //  4.7 MB
    float* STA   = (float*)w;  w += (size_t)BB * CHUNKS * DII * NSS * 4;  // 6.3 MB
    float* STH   = (float*)w;  w += (size_t)BB * CHUNKS * DII * NSS * 4;  // 6.3 MB

    float* out = (float*)d_out;

    // 0. weight prep
    k_cvt<<<(XZN * DMM + 255) / 256, 256, 0, stream>>>(W_in, WINH, XZN * DMM);
    k_cvt<<<(DMM * DII + 255) / 256, 256, 0, stream>>>(W_out, WOH, DMM * DII);
    k_w2<<<N2, 256, 0, stream>>>(W_x, b_x, W_dt, b_dt, W2H, BIAS2);

    // 1. norm -> f16
    k_norm<<<NROWS, 256, 0, stream>>>(hs, gamma, HSNH);

    // 2. xz = hsn @ W_in^T + b_in   (2048 x 3072 x 768), f16 out
    k_gemm64<0, h16><<<dim3(XZN / 64, NROWS / 64), 256, 0, stream>>>(
        HSNH, DMM, WINH, DMM, b_in, XZH, XZN, DMM, nullptr, nullptr);

    // 3. conv + dsp -> f16 xact
    k_conv<<<(NROWS * DII) / 256, 256, 0, stream>>>(XZH, conv_w, conv_b, XACTH);

    // 4. combined: [decay_mod | B | C] = xact @ W2^T + bias2  (2048 x 1664 x 1536), f16 out
    k_gemm64<0, h16><<<dim3(N2 / 64, NROWS / 64), 256, 0, stream>>>(
        XACTH, DII, W2H, DII, BIAS2, DMBCH, N2, DII, nullptr, nullptr);

    // 5. chunked scan (32 chunks x 32) + fused einsum + inline gate -> ygh (f16)
    k_scan_p1<<<BB * CHUNKS * 6, 256, 0, stream>>>(
        DMBCH, XACTH, base_dec, dec_shift, STA, STH);
    k_scan_p2<<<NCH / 256, 256, 0, stream>>>(STA, STH);
    k_scan_p3<<<BB * CHUNKS * 6, 256, 0, stream>>>(
        DMBCH, XACTH, XZH, base_dec, dec_shift, STA, YGH);

    // 6. out = resid + clip(yg @ W_out^T + b_out)*rg   (2048 x 768 x 1536)
    k_gemm64<1, float><<<dim3(DMM / 64, NROWS / 64), 256, 0, stream>>>(
        YGH, DII, WOH, DII, b_out, out, DMM, DII, hs, res_gate);
}

// Round 7
// 176.616 us; speedup vs baseline: 1.0548x; 1.0548x over previous
//
#include <hip/hip_runtime.h>
#include <hip/hip_bf16.h>
#include <stdint.h>

// Problem constants
#define BB  2
#define LL  1024
#define DMM 768
#define DII 1536
#define NSS 16
#define DTRR 48
#define XZN (2*DII)        // 3072
#define NROWS (BB*LL)      // 2048
#define N2 1664            // padded N for combined GEMM2 (1536 dmod + 32 B/C + 96 pad)

// chunked scan: one thread per (b, d, chunk), 16 n-states in registers
#define CHUNKS 64
#define CHLEN  (LL/CHUNKS)          // 16
#define NCH    (BB*DII*NSS)         // 49152 channels for p2

typedef _Float16 h16;
typedef __attribute__((ext_vector_type(8))) _Float16 h16x8;
typedef __attribute__((ext_vector_type(4))) float f32x4;

typedef const __attribute__((address_space(1))) uint32_t gau32;
typedef __attribute__((address_space(3))) uint32_t lau32;
#define GLL16(gp, lp) __builtin_amdgcn_global_load_lds((gau32*)(gp), (lau32*)(lp), 16, 0, 0)

__device__ __forceinline__ float dspf(float x) {
    return 0.25f * (x + sqrtf(x*x + 4.0f));
}
__device__ __forceinline__ float clampf(float x, float lo, float hi) {
    return fminf(fmaxf(x, lo), hi);
}

// ---------------------------------------------------------------------------
// f32 -> f16 convert
// ---------------------------------------------------------------------------
__global__ __launch_bounds__(256) void k_cvt(const float* __restrict__ in,
                                             h16* __restrict__ out, int n) {
    int i = blockIdx.x * 256 + threadIdx.x;
    if (i < n) out[i] = (h16)in[i];
}

// ---------------------------------------------------------------------------
// Build combined W2 [N2 x DII] (f16) + bias2 [N2] (f32)
// ---------------------------------------------------------------------------
__global__ __launch_bounds__(256) void k_w2(const float* __restrict__ W_x,
                                            const float* __restrict__ b_x,
                                            const float* __restrict__ W_dt,
                                            const float* __restrict__ b_dt,
                                            h16* __restrict__ W2,
                                            float* __restrict__ bias2) {
    int i = blockIdx.x;
    int tid = threadIdx.x;
    if (i < DII) {
        __shared__ float wd[DTRR];
        if (tid < DTRR) wd[tid] = W_dt[i * DTRR + tid];
        __syncthreads();
        for (int j = tid; j < DII; j += 256) {
            float s = 0.f;
            #pragma unroll
            for (int k = 0; k < DTRR; ++k) s = fmaf(wd[k], W_x[(size_t)k * DII + j], s);
            W2[(size_t)i * DII + j] = (h16)s;
        }
        if (tid == 0) {
            float s = b_dt[i];
            for (int k = 0; k < DTRR; ++k) s = fmaf(wd[k], b_x[k], s);
            bias2[i] = s;
        }
    } else if (i < DII + 2 * NSS) {
        int r = i - DII;
        for (int j = tid; j < DII; j += 256)
            W2[(size_t)i * DII + j] = (h16)W_x[(size_t)(DTRR + r) * DII + j];
        if (tid == 0) bias2[i] = b_x[DTRR + r];
    } else {
        for (int j = tid; j < DII; j += 256) W2[(size_t)i * DII + j] = (h16)0.f;
        if (tid == 0) bias2[i] = 0.f;
    }
}

// ---------------------------------------------------------------------------
// K1: norm -> f16 output
// ---------------------------------------------------------------------------
__global__ __launch_bounds__(256) void k_norm(const float* __restrict__ hs,
                                              const float* __restrict__ gamma,
                                              h16* __restrict__ out) {
    int row = blockIdx.x;
    const float* p = hs + (size_t)row * DMM;
    __shared__ float red[256];
    int tid = threadIdx.x;

    float s = 0.f;
    for (int i = tid; i < DMM; i += 256) s += p[i];
    red[tid] = s; __syncthreads();
    for (int off = 128; off > 0; off >>= 1) {
        if (tid < off) red[tid] += red[tid + off];
        __syncthreads();
    }
    float mean = red[0] / (float)DMM;
    __syncthreads();

    float v = 0.f;
    for (int i = tid; i < DMM; i += 256) { float d = p[i] - mean; v += d*d; }
    red[tid] = v; __syncthreads();
    for (int off = 128; off > 0; off >>= 1) {
        if (tid < off) red[tid] += red[tid + off];
        __syncthreads();
    }
    float var = red[0] / (float)DMM;
    float k = rintf(log2f(sqrtf(var + 1e-9f)));
    k = fmaxf(k, 0.f);
    float scale = exp2f(-k);
    for (int i = tid; i < DMM; i += 256)
        out[(size_t)row * DMM + i] = (h16)((p[i] - mean) * scale * gamma[i]);
}

// ---------------------------------------------------------------------------
// MFMA f16 GEMM, 64x64 tile, BK=64, 4 waves (each 32x32), double-buffered
// LDS with counted vmcnt(4). XCD-bijective block swizzle.
// EPI==1: out = resid + clip(acc+bias,±32000)*rg
// ---------------------------------------------------------------------------
template<int EPI, typename OutT>
__global__ __launch_bounds__(256) void k_gemm64(
    const h16* __restrict__ A, int lda,
    const h16* __restrict__ Bw, int ldb,
    const float* __restrict__ bias,
    OutT* __restrict__ C, int ldc, int K,
    const float* __restrict__ resid, const float* __restrict__ rgate)
{
    __shared__ __align__(16) h16 As[2][64 * 64];
    __shared__ __align__(16) h16 Bs[2][64 * 64];
    const int tid  = threadIdx.x;
    const int lane = tid & 63;
    const int wv   = tid >> 6;

    // XCD-aware bijective swizzle of the flat block id
    const int nwg = gridDim.x * gridDim.y;
    const int bid = blockIdx.y * gridDim.x + blockIdx.x;
    const int cpx = nwg >> 3;
    const int swz = (bid & 7) * cpx + (bid >> 3);
    const int bxi = swz % gridDim.x, byi = swz / gridDim.x;

    const int bm = byi * 64, bn = bxi * 64;
    const int wr = wv >> 1, wc = wv & 1;

    f32x4 acc[2][2] = {};

    const int srow = lane >> 3;                    // row within 8-row issue
    const int kbl  = ((lane & 7) ^ srow) * 8;      // pre-swizzled logical k-block
    const int KT = K / 64;

    #pragma unroll
    for (int q = 0; q < 2; ++q) {
        int row = (wv * 2 + q) * 8 + srow;
        GLL16(A  + (size_t)(bm + row) * lda + kbl, &As[0][(wv*2+q)*8*64]);
        GLL16(Bw + (size_t)(bn + row) * ldb + kbl, &Bs[0][(wv*2+q)*8*64]);
    }

    int buf = 0;
    for (int kt = 0; kt < KT; ++kt) {
        if (kt + 1 < KT) {
            int k0 = (kt + 1) * 64;
            #pragma unroll
            for (int q = 0; q < 2; ++q) {
                int row = (wv * 2 + q) * 8 + srow;
                GLL16(A  + (size_t)(bm + row) * lda + k0 + kbl, &As[buf^1][(wv*2+q)*8*64]);
                GLL16(Bw + (size_t)(bn + row) * ldb + k0 + kbl, &Bs[buf^1][(wv*2+q)*8*64]);
            }
            asm volatile("s_waitcnt vmcnt(4)" ::: "memory");
        } else {
            asm volatile("s_waitcnt vmcnt(0)" ::: "memory");
        }
        __syncthreads();

        const int r16 = lane & 15, kq = lane >> 4;
        #pragma unroll
        for (int kk = 0; kk < 2; ++kk) {
            h16x8 af[2], bf[2];
            #pragma unroll
            for (int i = 0; i < 2; ++i) {
                int rowA = wr * 32 + i * 16 + r16;
                af[i] = *(const h16x8*)&As[buf][rowA * 64 + (((kk*4 + kq) ^ (rowA & 7)) << 3)];
            }
            #pragma unroll
            for (int j = 0; j < 2; ++j) {
                int rowB = wc * 32 + j * 16 + r16;
                bf[j] = *(const h16x8*)&Bs[buf][rowB * 64 + (((kk*4 + kq) ^ (rowB & 7)) << 3)];
            }
            #pragma unroll
            for (int i = 0; i < 2; ++i)
                #pragma unroll
                for (int j = 0; j < 2; ++j)
                    acc[i][j] = __builtin_amdgcn_mfma_f32_16x16x32_f16(af[i], bf[j], acc[i][j], 0, 0, 0);
        }
        __syncthreads();
        buf ^= 1;
    }

    const int r4 = (lane >> 4) * 4;
    const int cn = lane & 15;
    float rg = 0.f;
    if (EPI) rg = rgate[0];
    #pragma unroll
    for (int i = 0; i < 2; ++i) {
        #pragma unroll
        for (int j = 0; j < 2; ++j) {
            int col = bn + wc * 32 + j * 16 + cn;
            float bv = bias[col];
            #pragma unroll
            for (int r = 0; r < 4; ++r) {
                int row = bm + wr * 32 + i * 16 + r4 + r;
                float v = acc[i][j][r] + bv;
                if (EPI) {
                    v = clampf(v, -32000.f, 32000.f);
                    v = resid[(size_t)row * ldc + col] + v * rg;
                }
                C[(size_t)row * ldc + col] = (OutT)v;
            }
        }
    }
}

// ---------------------------------------------------------------------------
// K3: depthwise causal conv (f16 in) + dsp -> f16 xact
// ---------------------------------------------------------------------------
__global__ __launch_bounds__(256) void k_conv(const h16* __restrict__ xz,
                                              const float* __restrict__ cw,
                                              const float* __restrict__ cb,
                                              h16* __restrict__ xacth)
{
    int idx = blockIdx.x * 256 + threadIdx.x;       // over B*L*DI
    if (idx >= NROWS * DII) return;
    int c = idx % DII;
    int bl = idx / DII;
    int l = bl % LL;
    int b = bl / LL;
    float acc = cb[c];
    #pragma unroll
    for (int j = 0; j < 4; ++j) {
        int ls = l - 3 + j;
        if (ls >= 0)
            acc = fmaf((float)xz[(size_t)(b * LL + ls) * XZN + c], cw[c * 4 + j], acc);
    }
    xacth[idx] = (h16)dspf(acc);
}

// ---------------------------------------------------------------------------
// Chunked scan. Thread = (b, chunk, d); 16 n-states in registers.
// stA/stH split arrays, index ((b*CHUNKS+chunk)*DII + d)*16 + n.
// p1 writes (A-product, h-end); p2 rewrites stA to the incoming prefix;
// p3 reads only stA.
// ---------------------------------------------------------------------------
__device__ __forceinline__ void load_setup(const float* __restrict__ basenum,
                                           const int* __restrict__ shifts,
                                           int d, float* base, float* p2c) {
    const float4* bp = (const float4*)(basenum + (size_t)d * NSS);
    const int4*   sp = (const int4*)(shifts + (size_t)d * NSS);
    #pragma unroll
    for (int q = 0; q < 4; ++q) {
        float4 bv = bp[q]; int4 sv = sp[q];
        base[q*4+0] = bv.x; base[q*4+1] = bv.y; base[q*4+2] = bv.z; base[q*4+3] = bv.w;
        p2c[q*4+0] = exp2f(-(float)sv.x);
        p2c[q*4+1] = exp2f(-(float)sv.y);
        p2c[q*4+2] = exp2f(-(float)sv.z);
        p2c[q*4+3] = exp2f(-(float)sv.w);
    }
}

__global__ __launch_bounds__(256) void k_scan_p1(
    const h16* __restrict__ dmbc,      // (B*L, N2) f16: [dmod 1536 | B 16 | C 16 | pad]
    const h16* __restrict__ xacth,     // (B*L, DI)
    const float* __restrict__ basenum, // (DI, NS)
    const int*   __restrict__ shifts,  // (DI, NS)
    float* __restrict__ stA, float* __restrict__ stH)
{
    int bc   = blockIdx.x / 6;              // b*CHUNKS + chunk  (uniform)
    int dblk = blockIdx.x % 6;
    int d    = dblk * 256 + threadIdx.x;
    int b    = bc / CHUNKS;
    int chunk= bc % CHUNKS;

    float base[16], p2c[16], h[16], A[16];
    load_setup(basenum, shifts, d, base, p2c);
    #pragma unroll
    for (int n = 0; n < 16; ++n) { h[n] = 0.f; A[n] = 1.f; }

    int row0 = b * LL + chunk * CHLEN;
    #pragma unroll 4
    for (int l = 0; l < CHLEN; ++l) {
        int row = row0 + l;
        float dm = (float)dmbc[(size_t)row * N2 + d];
        float xv = (float)xacth[(size_t)row * DII + d];
        float common = xv * (dspf(dm) * 0.1f);
        const h16x8* Bp = (const h16x8*)(dmbc + (size_t)row * N2 + DII);
        h16x8 b0 = Bp[0], b1 = Bp[1];
        float Bv[16];
        #pragma unroll
        for (int n = 0; n < 8; ++n) { Bv[n] = (float)b0[n]; Bv[8+n] = (float)b1[n]; }
        #pragma unroll
        for (int n = 0; n < 16; ++n) {
            float a = clampf(base[n] + dm, 0.f, 32767.f) * p2c[n];
            h[n] = fmaf(a, h[n], common * Bv[n]);
            A[n] *= a;
        }
    }
    size_t sb = ((size_t)bc * DII + d) * 16;
    float4* pa = (float4*)(stA + sb);
    float4* ph = (float4*)(stH + sb);
    #pragma unroll
    for (int q = 0; q < 4; ++q) {
        pa[q] = make_float4(A[q*4+0], A[q*4+1], A[q*4+2], A[q*4+3]);
        ph[q] = make_float4(h[q*4+0], h[q*4+1], h[q*4+2], h[q*4+3]);
    }
}

__global__ __launch_bounds__(256) void k_scan_p2(float* __restrict__ stA,
                                                 const float* __restrict__ stH)
{
    int ch = blockIdx.x * 256 + threadIdx.x;   // b*(DII*NSS) + d*16 + n
    int b  = ch / (DII * NSS);
    int rem = ch - b * (DII * NSS);
    float hin = 0.f;
    #pragma unroll 4
    for (int c = 0; c < CHUNKS; ++c) {
        size_t idx = ((size_t)(b * CHUNKS + c) * (DII * NSS)) + rem;
        float a = stA[idx], hh = stH[idx];
        stA[idx] = hin;
        hin = fmaf(a, hin, hh);
    }
}

__global__ __launch_bounds__(256) void k_scan_p3(
    const h16* __restrict__ dmbc,
    const h16* __restrict__ xacth,
    const h16* __restrict__ xz,        // for z -> gate
    const float* __restrict__ basenum,
    const int*   __restrict__ shifts,
    const float* __restrict__ stA,
    h16* __restrict__ ygh)             // (B*L, DI) = y * gate(z), f16
{
    int bc   = blockIdx.x / 6;
    int dblk = blockIdx.x % 6;
    int d    = dblk * 256 + threadIdx.x;
    int b    = bc / CHUNKS;
    int chunk= bc % CHUNKS;

    float base[16], p2c[16], h[16];
    load_setup(basenum, shifts, d, base, p2c);
    size_t sb = ((size_t)bc * DII + d) * 16;
    const float4* pa = (const float4*)(stA + sb);
    #pragma unroll
    for (int q = 0; q < 4; ++q) {
        float4 v = pa[q];
        h[q*4+0] = v.x; h[q*4+1] = v.y; h[q*4+2] = v.z; h[q*4+3] = v.w;
    }

    int row0 = b * LL + chunk * CHLEN;
    #pragma unroll 4
    for (int l = 0; l < CHLEN; ++l) {
        int row = row0 + l;
        float dm = (float)dmbc[(size_t)row * N2 + d];
        float xv = (float)xacth[(size_t)row * DII + d];
        float common = xv * (dspf(dm) * 0.1f);
        const h16x8* Bp = (const h16x8*)(dmbc + (size_t)row * N2 + DII);
        h16x8 b0 = Bp[0], b1 = Bp[1], c0 = Bp[2], c1 = Bp[3];
        float Bv[16], Cv[16];
        #pragma unroll
        for (int n = 0; n < 8; ++n) {
            Bv[n] = (float)b0[n]; Bv[8+n] = (float)b1[n];
            Cv[n] = (float)c0[n]; Cv[8+n] = (float)c1[n];
        }
        float y = 0.f;
        #pragma unroll
        for (int n = 0; n < 16; ++n) {
            float a = clampf(base[n] + dm, 0.f, 32767.f) * p2c[n];
            h[n] = fmaf(a, h[n], common * Bv[n]);
            float hc = clampf(h[n], -32000.f, 32000.f);
            y = fmaf(hc, Cv[n], y);
        }
        float z = (float)xz[(size_t)row * XZN + DII + d];
        float gate = 0.5f * (1.0f + z * rsqrtf(z * z + 1.0f));
        ygh[(size_t)row * DII + d] = (h16)(y * gate);
    }
}

// ---------------------------------------------------------------------------
extern "C" void kernel_launch(void* const* d_in, const int* in_sizes, int n_in,
                              void* d_out, int out_size, void* d_ws, size_t ws_size,
                              hipStream_t stream) {
    const float* hs        = (const float*)d_in[0];
    const float* gamma     = (const float*)d_in[1];
    const float* W_in      = (const float*)d_in[2];
    const float* b_in      = (const float*)d_in[3];
    const float* conv_w    = (const float*)d_in[4];
    const float* conv_b    = (const float*)d_in[5];
    const float* W_x       = (const float*)d_in[6];
    const float* b_x       = (const float*)d_in[7];
    const float* W_dt      = (const float*)d_in[8];
    const float* b_dt      = (const float*)d_in[9];
    const float* W_out     = (const float*)d_in[10];
    const float* b_out     = (const float*)d_in[11];
    const float* base_dec  = (const float*)d_in[12];
    const float* res_gate  = (const float*)d_in[13];
    const int*   dec_shift = (const int*)d_in[14];

    // workspace layout (bytes), no overlays
    char* w = (char*)d_ws;
    h16*   XZH   = (h16*)w;    w += (size_t)NROWS * XZN * 2;   // 12.6 MB
    h16*   XACTH = (h16*)w;    w += (size_t)NROWS * DII * 2;   //  6.3 MB
    h16*   DMBCH = (h16*)w;    w += (size_t)NROWS * N2  * 2;   //  6.8 MB
    h16*   W2H   = (h16*)w;    w += (size_t)N2 * DII * 2;      //  5.1 MB
    h16*   WOH   = (h16*)w;    w += (size_t)DMM * DII * 2;     //  2.4 MB
    float* BIAS2 = (float*)w;  w += 8192;
    h16*   YGH   = (h16*)w;    w += (size_t)NROWS * DII * 2;   //  6.3 MB
    h16*   HSNH  = (h16*)w;    w += (size_t)NROWS * DMM * 2;   //  3.1 MB
    h16*   WINH  = (h16*)w;    w += (size_t)XZN * DMM * 2;     //  4.7 MB
    float* STA   = (float*)w;  w += (size_t)BB * CHUNKS * DII * NSS * 4;  // 12.6 MB
    float* STH   = (float*)w;  w += (size_t)BB * CHUNKS * DII * NSS * 4;  // 12.6 MB

    float* out = (float*)d_out;

    // 0. weight prep
    k_cvt<<<(XZN * DMM + 255) / 256, 256, 0, stream>>>(W_in, WINH, XZN * DMM);
    k_cvt<<<(DMM * DII + 255) / 256, 256, 0, stream>>>(W_out, WOH, DMM * DII);
    k_w2<<<N2, 256, 0, stream>>>(W_x, b_x, W_dt, b_dt, W2H, BIAS2);

    // 1. norm -> f16
    k_norm<<<NROWS, 256, 0, stream>>>(hs, gamma, HSNH);

    // 2. xz = hsn @ W_in^T + b_in   (2048 x 3072 x 768), f16 out
    k_gemm64<0, h16><<<dim3(XZN / 64, NROWS / 64), 256, 0, stream>>>(
        HSNH, DMM, WINH, DMM, b_in, XZH, XZN, DMM, nullptr, nullptr);

    // 3. conv + dsp -> f16 xact
    k_conv<<<(NROWS * DII) / 256, 256, 0, stream>>>(XZH, conv_w, conv_b, XACTH);

    // 4. combined: [decay_mod | B | C] = xact @ W2^T + bias2  (2048 x 1664 x 1536), f16 out
    k_gemm64<0, h16><<<dim3(N2 / 64, NROWS / 64), 256, 0, stream>>>(
        XACTH, DII, W2H, DII, BIAS2, DMBCH, N2, DII, nullptr, nullptr);

    // 5. chunked scan (64 chunks x 16) + fused einsum + inline gate -> ygh (f16)
    k_scan_p1<<<BB * CHUNKS * 6, 256, 0, stream>>>(
        DMBCH, XACTH, base_dec, dec_shift, STA, STH);
    k_scan_p2<<<NCH / 256, 256, 0, stream>>>(STA, STH);
    k_scan_p3<<<BB * CHUNKS * 6, 256, 0, stream>>>(
        DMBCH, XACTH, XZH, base_dec, dec_shift, STA, YGH);

    // 6. out = resid + clip(yg @ W_out^T + b_out)*rg   (2048 x 768 x 1536)
    k_gemm64<1, float><<<dim3(DMM / 64, NROWS / 64), 256, 0, stream>>>(
        YGH, DII, WOH, DII, b_out, out, DMM, DII, hs, res_gate);
}